// Round 4
// baseline (239.468 us; speedup 1.0000x reference)
//
#include <hip/hip_runtime.h>

// Problem constants (fixed by the reference)
constexpr int C_ = 2048;
constexpr int H_ = 16;
constexpr int W_ = 16;
constexpr int F_ = 64;
constexpr int P_ = 256;                 // samples per complex
constexpr int MAP4 = H_ * W_ * F_ / 4;  // 4096 float4 = 64 KB
constexpr int BLK = 1024;               // 16 waves per block
constexpr int NBLOCKS = 256;            // one persistent block per CU
constexpr int NC = C_ / NBLOCKS;        // 8 complexes per block
constexpr int ITERS = P_ * 16 / BLK;    // 4 phase-2 passes (64 samples each)

// Round-3 lesson: 3 structurally different kernels all hit ~82us because they
// share read->barrier->write phase serialization: co-resident blocks stage and
// store in lockstep, so HBM reads never overlap HBM writes. 82us matches
// 8 x (5.2us read + 5.2us write) per CU done serially. Fix: persistent block
// per CU, double-buffered map LDS (2x64KB), DMA-prefetch complex c+1 while
// computing/storing complex c. One __syncthreads per phase (vmcnt drain +
// barrier) makes the buffer swap race-free.
// Second leak: out writes (128MB) evict map from the 256MB L3 -> 64MB HBM
// re-fetch every dispatch. out is never read: use non-temporal stores.
typedef __attribute__((address_space(3))) uint32_t lds_u32;
typedef const __attribute__((address_space(1))) uint32_t glb_u32;
using f32x4 = __attribute__((ext_vector_type(4))) float;

__global__ __launch_bounds__(BLK, 4) void ngf_fetch_kernel(
    const float* __restrict__ map_,
    const float* __restrict__ u_,
    const float* __restrict__ v_,
    float* __restrict__ out_) {
  __shared__ float4 smap[2][MAP4];   // 128 KB: double-buffered map tiles
  __shared__ float4 s_w[2][P_];      // (w00,w01,w10,w11) per sample, x2
  __shared__ int    s_ix[2][P_];     // (y0*W+x0)*(F/4) in float4 units, x2

  const int b = blockIdx.x;
  const int tid = threadIdx.x;
  const int f = tid & 15;        // float4 index along feature dim (0..15)
  const int sbase = tid >> 4;    // 0..63

  // ---- prologue: stage complex (i=0) = b ----
  {
    const float4* __restrict__ g =
        (const float4*)(map_ + (size_t)b * (H_ * W_ * F_));
#pragma unroll
    for (int k = 0; k < MAP4 / BLK; ++k) {
      __builtin_amdgcn_global_load_lds((glb_u32*)(g + k * BLK + tid),
                                       (lds_u32*)(&smap[0][k * BLK + tid]),
                                       16, 0, 0);
    }
    if (tid < P_) {
      const float x = u_[(size_t)b * P_ + tid] * (float)(W_ - 1);
      const float y = v_[(size_t)b * P_ + tid] * (float)(H_ - 1);
      int x0 = (int)floorf(x);
      int y0 = (int)floorf(y);
      x0 = x0 < 0 ? 0 : (x0 > W_ - 2 ? W_ - 2 : x0);
      y0 = y0 < 0 ? 0 : (y0 > H_ - 2 ? H_ - 2 : y0);
      const float fx = x - (float)x0;
      const float fy = y - (float)y0;
      const float wx0 = 1.0f - fx;
      const float wy0 = 1.0f - fy;
      s_w[0][tid] = make_float4(wx0 * wy0, fx * wy0, wx0 * fy, fx * fy);
      s_ix[0][tid] = (y0 * W_ + x0) * (F_ / 4);
    }
  }
  __syncthreads();   // vmcnt(0) drain: DMA(0) landed; coeffs(0) visible

  // ---- pipelined main loop: DMA(c+1) in flight during compute/store(c) ----
#pragma unroll
  for (int i = 0; i < NC; ++i) {
    const int cur = i & 1;
    const int nxt = cur ^ 1;
    const int c = i * NBLOCKS + b;       // contiguous sweep across the chip

    // 1) fire-and-forget DMA for next complex into the other buffer
    if (i + 1 < NC) {
      const int cn = (i + 1) * NBLOCKS + b;
      const float4* __restrict__ g =
          (const float4*)(map_ + (size_t)cn * (H_ * W_ * F_));
#pragma unroll
      for (int k = 0; k < MAP4 / BLK; ++k) {
        __builtin_amdgcn_global_load_lds((glb_u32*)(g + k * BLK + tid),
                                         (lds_u32*)(&smap[nxt][k * BLK + tid]),
                                         16, 0, 0);
      }
    }

    // 2) prefetch u,v for next complex (latency hides under compute below)
    float un = 0.0f, vn = 0.0f;
    if (i + 1 < NC && tid < P_) {
      const int cn = (i + 1) * NBLOCKS + b;
      un = u_[(size_t)cn * P_ + tid];
      vn = v_[(size_t)cn * P_ + tid];
    }

    // 3) compute + store current complex from smap[cur]
    float4 w[ITERS];
    int ix[ITERS];
#pragma unroll
    for (int it = 0; it < ITERS; ++it) {
      const int s = it * (BLK / 16) + sbase;
      w[it] = s_w[cur][s];
      ix[it] = s_ix[cur][s] + f;
    }
    float4* __restrict__ gout = (float4*)(out_ + (size_t)c * (P_ * F_));
#pragma unroll
    for (int it = 0; it < ITERS; ++it) {
      const int s = it * (BLK / 16) + sbase;
      const float4 g00 = smap[cur][ix[it]];
      const float4 g01 = smap[cur][ix[it] + (F_ / 4)];            // x0+1
      const float4 g10 = smap[cur][ix[it] + W_ * (F_ / 4)];       // y0+1
      const float4 g11 = smap[cur][ix[it] + (W_ + 1) * (F_ / 4)]; // y0+1,x0+1

      f32x4 r;
      r.x = g00.x * w[it].x + g01.x * w[it].y + g10.x * w[it].z + g11.x * w[it].w;
      r.y = g00.y * w[it].x + g01.y * w[it].y + g10.y * w[it].z + g11.y * w[it].w;
      r.z = g00.z * w[it].x + g01.z * w[it].y + g10.z * w[it].z + g11.z * w[it].w;
      r.w = g00.w * w[it].x + g01.w * w[it].y + g10.w * w[it].z + g11.w * w[it].w;

      // out is write-only: non-temporal keeps map resident in L3
      __builtin_nontemporal_store(r, (f32x4*)(gout + s * (F_ / 4) + f));
    }

    // 4) coefficients for next complex into the other coeff buffer
    if (i + 1 < NC && tid < P_) {
      const float x = un * (float)(W_ - 1);
      const float y = vn * (float)(H_ - 1);
      int x0 = (int)floorf(x);
      int y0 = (int)floorf(y);
      x0 = x0 < 0 ? 0 : (x0 > W_ - 2 ? W_ - 2 : x0);
      y0 = y0 < 0 ? 0 : (y0 > H_ - 2 ? H_ - 2 : y0);
      const float fx = x - (float)x0;
      const float fy = y - (float)y0;
      const float wx0 = 1.0f - fx;
      const float wy0 = 1.0f - fy;
      s_w[nxt][tid] = make_float4(wx0 * wy0, fx * wy0, wx0 * fy, fx * fy);
      s_ix[nxt][tid] = (y0 * W_ + x0) * (F_ / 4);
    }

    __syncthreads();   // drain own DMA(c+1)+stores, publish coeffs(c+1)
  }
}

extern "C" void kernel_launch(void* const* d_in, const int* in_sizes, int n_in,
                              void* d_out, int out_size, void* d_ws, size_t ws_size,
                              hipStream_t stream) {
  const float* map_ = (const float*)d_in[0];
  const float* u_   = (const float*)d_in[1];
  const float* v_   = (const float*)d_in[2];
  float* out_ = (float*)d_out;

  ngf_fetch_kernel<<<NBLOCKS, BLK, 0, stream>>>(map_, u_, v_, out_);
}